// Round 1
// baseline (576.855 us; speedup 1.0000x reference)
//
#include <hip/hip_runtime.h>
#include <math.h>

#define NEG_SLOPE 0.2f
constexpr int BS_SCAN = 1024;

__device__ __forceinline__ float lrelu(float x) { return x > 0.f ? x : NEG_SLOPE * x; }

// ---------------- CSR build (group edges by dst) ----------------
__global__ void count_kernel(const int* __restrict__ dst, int* __restrict__ counts, int E) {
    int e = blockIdx.x * blockDim.x + threadIdx.x;
    if (e < E) atomicAdd(&counts[dst[e]], 1);
}

__global__ void scan1_kernel(const int* __restrict__ counts, int* __restrict__ excl,
                             int* __restrict__ totals, int n) {
    __shared__ int sm[BS_SCAN];
    int tid = threadIdx.x;
    int i = blockIdx.x * BS_SCAN + tid;
    int v = (i < n) ? counts[i] : 0;
    int val = v;
    sm[tid] = val;
    for (int off = 1; off < BS_SCAN; off <<= 1) {
        __syncthreads();
        int t = (tid >= off) ? sm[tid - off] : 0;
        __syncthreads();
        val += t; sm[tid] = val;
    }
    if (i < n) excl[i] = val - v;                 // exclusive within block
    if (tid == BS_SCAN - 1) totals[blockIdx.x] = val;
}

__global__ void scan2_kernel(int* totals, int nb) {  // one block of 256; nb <= 256
    __shared__ int sm[256];
    int tid = threadIdx.x;
    int v = (tid < nb) ? totals[tid] : 0;
    int val = v; sm[tid] = val;
    for (int off = 1; off < 256; off <<= 1) {
        __syncthreads();
        int t = (tid >= off) ? sm[tid - off] : 0;
        __syncthreads();
        val += t; sm[tid] = val;
    }
    if (tid < nb) totals[tid] = val - v;          // exclusive block offsets
}

__global__ void scan3_kernel(int* __restrict__ row_ptr, const int* __restrict__ totals,
                             int* __restrict__ cursor, int n, int E) {
    int i = blockIdx.x * BS_SCAN + threadIdx.x;
    if (i < n) {
        int rp = row_ptr[i] + totals[blockIdx.x];
        row_ptr[i] = rp;
        cursor[i] = rp;
    }
    if (i == 0) row_ptr[n] = E;
}

__global__ void scatter_kernel(const int* __restrict__ src, const int* __restrict__ dst,
                               int* __restrict__ cursor, int* __restrict__ col, int E) {
    int e = blockIdx.x * blockDim.x + threadIdx.x;
    if (e < E) {
        int d = dst[e];
        int pos = atomicAdd(&cursor[d], 1);
        col[pos] = src[e];
    }
}

// ---------------- dense GEMM: H[n,DOUT] = X[n,128] @ W[128,DOUT] ----------------
template<int DOUT>
__global__ __launch_bounds__(256) void gemm_kernel(const float* __restrict__ X,
                                                   const float* __restrict__ W,
                                                   float* __restrict__ H, int n) {
    constexpr int CT = DOUT / 4;            // threads along cols
    constexpr int ROWS = (256 / CT) * 4;    // rows per block
    int t = threadIdx.x;
    int c0 = (t % CT) * 4;
    int r0 = blockIdx.x * ROWS + (t / CT) * 4;
    float acc[4][4] = {};
    for (int k = 0; k < 128; k += 4) {
        float w[4][4];
        #pragma unroll
        for (int kk = 0; kk < 4; ++kk) {
            float4 wv = *reinterpret_cast<const float4*>(&W[(k + kk) * DOUT + c0]);
            w[kk][0] = wv.x; w[kk][1] = wv.y; w[kk][2] = wv.z; w[kk][3] = wv.w;
        }
        #pragma unroll
        for (int i = 0; i < 4; ++i) {
            int r = r0 + i;
            float4 xv = (r < n) ? *reinterpret_cast<const float4*>(&X[r * 128 + k])
                                : make_float4(0.f, 0.f, 0.f, 0.f);
            float xk[4] = {xv.x, xv.y, xv.z, xv.w};
            #pragma unroll
            for (int kk = 0; kk < 4; ++kk)
                #pragma unroll
                for (int j = 0; j < 4; ++j)
                    acc[i][j] += xk[kk] * w[kk][j];
        }
    }
    #pragma unroll
    for (int i = 0; i < 4; ++i) {
        int r = r0 + i;
        if (r < n)
            *reinterpret_cast<float4*>(&H[r * DOUT + c0]) =
                make_float4(acc[i][0], acc[i][1], acc[i][2], acc[i][3]);
    }
}

// ---------------- per-node attention logits: as = h.a_src, ad = h.a_dst ----------------
template<int DOUT>
__global__ void attn_dots_kernel(const float* __restrict__ H, const float* __restrict__ a_src,
                                 const float* __restrict__ a_dst, float* __restrict__ as_out,
                                 float* __restrict__ ad_out, int n) {
    int lane = threadIdx.x & 63;
    int node = blockIdx.x * 4 + (threadIdx.x >> 6);
    if (node >= n) return;
    float s = 0.f, d = 0.f;
    #pragma unroll
    for (int c = lane; c < DOUT; c += 64) {
        float hv = H[node * DOUT + c];
        s += hv * a_src[c];
        d += hv * a_dst[c];
    }
    for (int off = 32; off; off >>= 1) { s += __shfl_down(s, off); d += __shfl_down(d, off); }
    if (lane == 0) { as_out[node] = s; ad_out[node] = d; }
}

// ---------------- segment softmax + weighted aggregation (one wave per dst node) ----------------
// MODE 0: out = SiLU(agg + b)   (DOUT=128)
// MODE 1: out = log_softmax(agg + b) across 64 classes (DOUT=64)
template<int DOUT, int MODE>
__global__ void aggregate_kernel(const float* __restrict__ H, const float* __restrict__ as_v,
                                 const float* __restrict__ ad_v, const float* __restrict__ bias,
                                 const int* __restrict__ row_ptr, const int* __restrict__ col,
                                 float* __restrict__ out, int n) {
    int lane = threadIdx.x & 63;
    int node = blockIdx.x * 4 + (threadIdx.x >> 6);
    if (node >= n) return;
    int beg = row_ptr[node], end = row_ptr[node + 1];
    float adv = ad_v[node];
    float alpha_self = lrelu(as_v[node] + adv);     // implicit self-loop (src=dst=node)

    // pass 1: segment max (lanes stride over edges)
    float m = alpha_self;
    for (int e = beg + lane; e < end; e += 64)
        m = fmaxf(m, lrelu(as_v[col[e]] + adv));
    for (int off = 32; off; off >>= 1) m = fmaxf(m, __shfl_down(m, off));
    m = __shfl(m, 0);

    // pass 2: denom = sum exp(alpha - m)
    float dsum = (lane == 0) ? __expf(alpha_self - m) : 0.f;
    for (int e = beg + lane; e < end; e += 64)
        dsum += __expf(lrelu(as_v[col[e]] + adv) - m);
    for (int off = 32; off; off >>= 1) dsum += __shfl_down(dsum, off);
    dsum = __shfl(dsum, 0);
    float inv = 1.f / dsum;

    // pass 3: weighted sum of h[src] rows; lanes own feature channels
    float coef_self = __expf(alpha_self - m) * inv;
    float acc0 = coef_self * H[node * DOUT + lane];
    float acc1 = (DOUT == 128) ? coef_self * H[node * DOUT + lane + 64] : 0.f;
    for (int e = beg; e < end; ++e) {
        int s = col[e];                              // wave-uniform
        float coef = __expf(lrelu(as_v[s] + adv) - m) * inv;
        acc0 += coef * H[s * DOUT + lane];
        if (DOUT == 128) acc1 += coef * H[s * DOUT + lane + 64];
    }

    if (MODE == 0) {
        float v0 = acc0 + bias[lane];
        out[node * DOUT + lane] = v0 / (1.f + __expf(-v0));
        if (DOUT == 128) {
            float v1 = acc1 + bias[lane + 64];
            out[node * DOUT + lane + 64] = v1 / (1.f + __expf(-v1));
        }
    } else {
        float v = acc0 + bias[lane];
        float mx = v;
        for (int off = 32; off; off >>= 1) mx = fmaxf(mx, __shfl_down(mx, off));
        mx = __shfl(mx, 0);
        float ex = __expf(v - mx);
        float sum = ex;
        for (int off = 32; off; off >>= 1) sum += __shfl_down(sum, off);
        sum = __shfl(sum, 0);
        out[node * DOUT + lane] = v - mx - logf(sum);
    }
}

extern "C" void kernel_launch(void* const* d_in, const int* in_sizes, int n_in,
                              void* d_out, int out_size, void* d_ws, size_t ws_size,
                              hipStream_t stream) {
    const float* x   = (const float*)d_in[0];
    const int*   ei  = (const int*)d_in[1];
    const float* W0  = (const float*)d_in[2];
    const float* as0 = (const float*)d_in[3];
    const float* ad0 = (const float*)d_in[4];
    const float* b0  = (const float*)d_in[5];
    const float* W1  = (const float*)d_in[6];
    const float* as1 = (const float*)d_in[7];
    const float* ad1 = (const float*)d_in[8];
    const float* b1  = (const float*)d_in[9];
    const float* W2  = (const float*)d_in[10];
    const float* as2 = (const float*)d_in[11];
    const float* ad2 = (const float*)d_in[12];
    const float* b2  = (const float*)d_in[13];

    int n = in_sizes[0] / 128;
    int E = in_sizes[1] / 2;
    const int* srcv = ei;
    const int* dstv = ei + E;

    char* wsp = (char*)d_ws;
    auto alloc = [&](size_t bytes) {
        char* p = wsp;
        wsp += (bytes + 255) & ~(size_t)255;
        return p;
    };
    int*   counts  = (int*)alloc((size_t)n * 4);
    int*   row_ptr = (int*)alloc((size_t)(n + 1) * 4);
    int*   cursor  = (int*)alloc((size_t)n * 4);
    int*   totals  = (int*)alloc(256 * 4);
    int*   col     = (int*)alloc((size_t)E * 4);
    float* h       = (float*)alloc((size_t)n * 128 * 4);
    float* xb      = (float*)alloc((size_t)n * 128 * 4);
    float* asb     = (float*)alloc((size_t)n * 4);
    float* adb     = (float*)alloc((size_t)n * 4);

    // ---- CSR build ----
    hipMemsetAsync(counts, 0, (size_t)n * 4, stream);
    int eb = (E + 255) / 256;
    count_kernel<<<eb, 256, 0, stream>>>(dstv, counts, E);
    int nb = (n + BS_SCAN - 1) / BS_SCAN;   // 49 for n=50000, fits scan2's 256
    scan1_kernel<<<nb, BS_SCAN, 0, stream>>>(counts, row_ptr, totals, n);
    scan2_kernel<<<1, 256, 0, stream>>>(totals, nb);
    scan3_kernel<<<nb, BS_SCAN, 0, stream>>>(row_ptr, totals, cursor, n, E);
    scatter_kernel<<<eb, 256, 0, stream>>>(srcv, dstv, cursor, col, E);

    int nodeb = (n + 3) / 4;

    // ---- layer 0: 128 -> 128, SiLU ----
    gemm_kernel<128><<<(n + 31) / 32, 256, 0, stream>>>(x, W0, h, n);
    attn_dots_kernel<128><<<nodeb, 256, 0, stream>>>(h, as0, ad0, asb, adb, n);
    aggregate_kernel<128, 0><<<nodeb, 256, 0, stream>>>(h, asb, adb, b0, row_ptr, col, xb, n);

    // ---- layer 1: 128 -> 128, SiLU ----
    gemm_kernel<128><<<(n + 31) / 32, 256, 0, stream>>>(xb, W1, h, n);
    attn_dots_kernel<128><<<nodeb, 256, 0, stream>>>(h, as1, ad1, asb, adb, n);
    aggregate_kernel<128, 0><<<nodeb, 256, 0, stream>>>(h, asb, adb, b1, row_ptr, col, xb, n);

    // ---- layer 2: 128 -> 64, log_softmax ----
    gemm_kernel<64><<<(n + 63) / 64, 256, 0, stream>>>(xb, W2, h, n);
    attn_dots_kernel<64><<<nodeb, 256, 0, stream>>>(h, as2, ad2, asb, adb, n);
    aggregate_kernel<64, 1><<<nodeb, 256, 0, stream>>>(h, asb, adb, b2, row_ptr, col, (float*)d_out, n);
}

// Round 3
// 336.677 us; speedup vs baseline: 1.7134x; 1.7134x over previous
//
#include <hip/hip_runtime.h>
#include <math.h>

#define NEG_SLOPE 0.2f
constexpr int BS_SCAN = 1024;

typedef __attribute__((ext_vector_type(8))) short bfrag;   // 8 x bf16
typedef __attribute__((ext_vector_type(4))) float f32x4;

__device__ __forceinline__ float lrelu(float x) { return x > 0.f ? x : NEG_SLOPE * x; }

__device__ __forceinline__ unsigned short f2bf(float f) {
    union { float f; unsigned u; } v; v.f = f;
    unsigned r = v.u + 0x7fffu + ((v.u >> 16) & 1u);   // RNE
    return (unsigned short)(r >> 16);
}
__device__ __forceinline__ float bf2f_lo(unsigned p) { union { unsigned u; float f; } v; v.u = p << 16; return v.f; }
__device__ __forceinline__ float bf2f_hi(unsigned p) { union { unsigned u; float f; } v; v.u = p & 0xffff0000u; return v.f; }

// ---------------- CSR build (group edges by dst) ----------------
__global__ void count_kernel(const int* __restrict__ dst, int* __restrict__ counts, int E) {
    int e = blockIdx.x * blockDim.x + threadIdx.x;
    if (e < E) atomicAdd(&counts[dst[e]], 1);
}

__global__ void scan1_kernel(const int* __restrict__ counts, int* __restrict__ excl,
                             int* __restrict__ totals, int n) {
    __shared__ int sm[BS_SCAN];
    int tid = threadIdx.x;
    int i = blockIdx.x * BS_SCAN + tid;
    int v = (i < n) ? counts[i] : 0;
    int val = v;
    sm[tid] = val;
    for (int off = 1; off < BS_SCAN; off <<= 1) {
        __syncthreads();
        int t = (tid >= off) ? sm[tid - off] : 0;
        __syncthreads();
        val += t; sm[tid] = val;
    }
    if (i < n) excl[i] = val - v;
    if (tid == BS_SCAN - 1) totals[blockIdx.x] = val;
}

__global__ void scan2_kernel(int* totals, int nb) {
    __shared__ int sm[256];
    int tid = threadIdx.x;
    int v = (tid < nb) ? totals[tid] : 0;
    int val = v; sm[tid] = val;
    for (int off = 1; off < 256; off <<= 1) {
        __syncthreads();
        int t = (tid >= off) ? sm[tid - off] : 0;
        __syncthreads();
        val += t; sm[tid] = val;
    }
    if (tid < nb) totals[tid] = val - v;
}

__global__ void scan3_kernel(int* __restrict__ row_ptr, const int* __restrict__ totals,
                             int* __restrict__ cursor, int n, int E) {
    int i = blockIdx.x * BS_SCAN + threadIdx.x;
    if (i < n) {
        int rp = row_ptr[i] + totals[blockIdx.x];
        row_ptr[i] = rp;
        cursor[i] = rp;
    }
    if (i == 0) row_ptr[n] = E;
}

__global__ void scatter_kernel(const int* __restrict__ src, const int* __restrict__ dst,
                               int* __restrict__ cursor, int* __restrict__ col, int E) {
    int e = blockIdx.x * blockDim.x + threadIdx.x;
    if (e < E) {
        int d = dst[e];
        int pos = atomicAdd(&cursor[d], 1);
        col[pos] = src[e];
    }
}

// ---------------- W swizzle: fp32 [128,DOUT] -> bf16 B-fragment order ----------------
// Layout: [kstep][tile][lane][8], element j = W[kstep*32 + (lane>>4)*8 + j][tile*16 + (lane&15)]
__global__ void wswz_kernel(const float* __restrict__ W, unsigned short* __restrict__ out,
                            int DOUT, int total) {
    int tid = blockIdx.x * blockDim.x + threadIdx.x;
    if (tid >= total) return;
    int lane = tid & 63;
    int g = tid >> 6;
    int NT = DOUT >> 4;
    int tile = g % NT, kstep = g / NT;
    int q = lane >> 4, c = lane & 15;
    int n_ = tile * 16 + c;
    unsigned short v[8];
#pragma unroll
    for (int j = 0; j < 8; ++j) {
        int k = kstep * 32 + q * 8 + j;
        v[j] = f2bf(W[k * DOUT + n_]);
    }
    uint4 o;
    o.x = (unsigned)v[0] | ((unsigned)v[1] << 16);
    o.y = (unsigned)v[2] | ((unsigned)v[3] << 16);
    o.z = (unsigned)v[4] | ((unsigned)v[5] << 16);
    o.w = (unsigned)v[6] | ((unsigned)v[7] << 16);
    *(uint4*)(out + (size_t)tid * 8) = o;
}

// ---------------- fused GEMM (bf16 MFMA) + attention dots ----------------
// H[n,DOUT] = X[n,128] @ W[128,DOUT]; as_out = H.a_src; ad_out = H.a_dst
// DOUT==128: Hout is bf16 (packed uint); DOUT==64: Hout is fp32.
template<int DOUT, bool ABF>
__global__ __launch_bounds__(256) void gemm_fused_kernel(
    const void* __restrict__ Xv, const unsigned short* __restrict__ Wswz,
    const float* __restrict__ avs, const float* __restrict__ avd,
    void* __restrict__ Hout, float* __restrict__ as_out, float* __restrict__ ad_out, int n)
{
    constexpr int NT = DOUT / 16;
    __shared__ float smem[4][16 * 132];
    int w = threadIdx.x >> 6, lane = threadIdx.x & 63;
    int q = lane >> 4, c = lane & 15;
    int rowbase = blockIdx.x * 64 + w * 16;
    int arow = rowbase + c;

    f32x4 acc[NT];
#pragma unroll
    for (int t = 0; t < NT; ++t) acc[t] = (f32x4){0.f, 0.f, 0.f, 0.f};

#pragma unroll
    for (int ks = 0; ks < 4; ++ks) {
        bfrag a = (bfrag)0;
        int k0 = ks * 32 + q * 8;
        if (ABF) {
            if (arow < n) a = *(const bfrag*)((const unsigned short*)Xv + (size_t)arow * 128 + k0);
        } else {
            if (arow < n) {
                const float* xp = (const float*)Xv + (size_t)arow * 128 + k0;
                float4 x0 = *(const float4*)xp, x1 = *(const float4*)(xp + 4);
                a[0] = (short)f2bf(x0.x); a[1] = (short)f2bf(x0.y);
                a[2] = (short)f2bf(x0.z); a[3] = (short)f2bf(x0.w);
                a[4] = (short)f2bf(x1.x); a[5] = (short)f2bf(x1.y);
                a[6] = (short)f2bf(x1.z); a[7] = (short)f2bf(x1.w);
            }
        }
#pragma unroll
        for (int t = 0; t < NT; ++t) {
            bfrag b = *(const bfrag*)(Wswz + ((size_t)(ks * NT + t) * 64 + lane) * 8);
            acc[t] = __builtin_amdgcn_mfma_f32_16x16x32_bf16(a, b, acc[t], 0, 0, 0);
        }
    }

    // C/D layout: col = lane&15, row = (lane>>4)*4 + reg  -> repack via per-wave LDS
    float* sm = smem[w];
#pragma unroll
    for (int t = 0; t < NT; ++t)
#pragma unroll
        for (int r = 0; r < 4; ++r)
            sm[(q * 4 + r) * 132 + t * 16 + c] = acc[t][r];
    __builtin_amdgcn_wave_barrier();   // wave-private LDS RAW; DS pipe is in-order per wave

    if (DOUT == 128) {
#pragma unroll
        for (int it = 0; it < 4; ++it) {
            int r = it * 4 + q;
            int grow = rowbase + r;
            const float* rp = sm + r * 132 + c * 8;
            float4 xa = *(const float4*)rp, xb4 = *(const float4*)(rp + 4);
            uint4 o;
            o.x = (unsigned)f2bf(xa.x) | ((unsigned)f2bf(xa.y) << 16);
            o.y = (unsigned)f2bf(xa.z) | ((unsigned)f2bf(xa.w) << 16);
            o.z = (unsigned)f2bf(xb4.x) | ((unsigned)f2bf(xb4.y) << 16);
            o.w = (unsigned)f2bf(xb4.z) | ((unsigned)f2bf(xb4.w) << 16);
            if (grow < n) *(uint4*)((unsigned*)Hout + (size_t)grow * 64 + c * 4) = o;
        }
    } else {
#pragma unroll
        for (int it = 0; it < 4; ++it) {
            int r = it * 4 + q;
            int grow = rowbase + r;
            float4 v = *(const float4*)(sm + r * 132 + c * 4);
            if (grow < n) *(float4*)((float*)Hout + (size_t)grow * 64 + c * 4) = v;
        }
    }

    // dots: 4 lanes per row, each covers DOUT/4 consecutive cols
    int dr = lane >> 2;
    int c0 = (lane & 3) * (DOUT / 4);
    float s = 0.f, d = 0.f;
#pragma unroll
    for (int j = 0; j < DOUT / 4; j += 4) {
        float4 hv = *(const float4*)(sm + dr * 132 + c0 + j);
        float4 av = *(const float4*)(avs + c0 + j);
        float4 dv = *(const float4*)(avd + c0 + j);
        s += hv.x * av.x + hv.y * av.y + hv.z * av.z + hv.w * av.w;
        d += hv.x * dv.x + hv.y * dv.y + hv.z * dv.z + hv.w * dv.w;
    }
    s += __shfl_down(s, 2); s += __shfl_down(s, 1);
    d += __shfl_down(d, 2); d += __shfl_down(d, 1);
    int grow = rowbase + dr;
    if ((lane & 3) == 0 && grow < n) { as_out[grow] = s; ad_out[grow] = d; }
}

// ---------------- aggregation, DOUT=128, bf16 h payload, SiLU, bf16 out ----------------
__global__ __launch_bounds__(256) void agg128_kernel(
    const unsigned* __restrict__ Hb, const float* __restrict__ as_v,
    const float* __restrict__ ad_v, const float* __restrict__ bias,
    const int* __restrict__ row_ptr, const int* __restrict__ col,
    unsigned* __restrict__ outb, int n)
{
    int lane = threadIdx.x & 63;
    int node = blockIdx.x * 4 + (threadIdx.x >> 6);
    if (node >= n) return;
    int beg = row_ptr[node], end = row_ptr[node + 1];
    float adv = ad_v[node];
    float a_self = lrelu(as_v[node] + adv);

    float m = a_self;
    for (int e = beg + lane; e < end; e += 64) m = fmaxf(m, lrelu(as_v[col[e]] + adv));
#pragma unroll
    for (int off = 32; off; off >>= 1) m = fmaxf(m, __shfl_xor(m, off));

    float ds = (lane == 0) ? __expf(a_self - m) : 0.f;
    for (int e = beg + lane; e < end; e += 64) ds += __expf(lrelu(as_v[col[e]] + adv) - m);
#pragma unroll
    for (int off = 32; off; off >>= 1) ds += __shfl_xor(ds, off);
    float inv = 1.f / ds;

    float cs = __expf(a_self - m) * inv;
    unsigned p = Hb[(size_t)node * 64 + lane];
    float acc0 = cs * bf2f_lo(p), acc1 = cs * bf2f_hi(p);

    for (int cb = beg; cb < end; cb += 64) {
        int idx = cb + lane;
        int sreg = 0; float creg = 0.f;
        if (idx < end) { sreg = col[idx]; creg = __expf(lrelu(as_v[sreg] + adv) - m) * inv; }
        int cnt = end - cb; if (cnt > 64) cnt = 64;
        int k = 0;
        for (; k + 4 <= cnt; k += 4) {
            int i0 = __shfl(sreg, k), i1 = __shfl(sreg, k + 1),
                i2 = __shfl(sreg, k + 2), i3 = __shfl(sreg, k + 3);
            float c0 = __shfl(creg, k), c1 = __shfl(creg, k + 1),
                  c2 = __shfl(creg, k + 2), c3 = __shfl(creg, k + 3);
            unsigned p0 = Hb[(size_t)i0 * 64 + lane], p1 = Hb[(size_t)i1 * 64 + lane],
                     p2 = Hb[(size_t)i2 * 64 + lane], p3 = Hb[(size_t)i3 * 64 + lane];
            acc0 += c0 * bf2f_lo(p0); acc1 += c0 * bf2f_hi(p0);
            acc0 += c1 * bf2f_lo(p1); acc1 += c1 * bf2f_hi(p1);
            acc0 += c2 * bf2f_lo(p2); acc1 += c2 * bf2f_hi(p2);
            acc0 += c3 * bf2f_lo(p3); acc1 += c3 * bf2f_hi(p3);
        }
        for (; k < cnt; ++k) {
            int i0 = __shfl(sreg, k); float c0 = __shfl(creg, k);
            unsigned p0 = Hb[(size_t)i0 * 64 + lane];
            acc0 += c0 * bf2f_lo(p0); acc1 += c0 * bf2f_hi(p0);
        }
    }

    float2 bv = *(const float2*)(bias + lane * 2);
    float v0 = acc0 + bv.x, v1 = acc1 + bv.y;
    v0 = v0 / (1.f + __expf(-v0));
    v1 = v1 / (1.f + __expf(-v1));
    outb[(size_t)node * 64 + lane] = (unsigned)f2bf(v0) | ((unsigned)f2bf(v1) << 16);
}

// ---------------- aggregation, DOUT=64, fp32 h, log_softmax out ----------------
__global__ __launch_bounds__(256) void agg64_kernel(
    const float* __restrict__ Hf, const float* __restrict__ as_v,
    const float* __restrict__ ad_v, const float* __restrict__ bias,
    const int* __restrict__ row_ptr, const int* __restrict__ col,
    float* __restrict__ out, int n)
{
    int lane = threadIdx.x & 63;
    int node = blockIdx.x * 4 + (threadIdx.x >> 6);
    if (node >= n) return;
    int beg = row_ptr[node], end = row_ptr[node + 1];
    float adv = ad_v[node];
    float a_self = lrelu(as_v[node] + adv);

    float m = a_self;
    for (int e = beg + lane; e < end; e += 64) m = fmaxf(m, lrelu(as_v[col[e]] + adv));
#pragma unroll
    for (int off = 32; off; off >>= 1) m = fmaxf(m, __shfl_xor(m, off));

    float ds = (lane == 0) ? __expf(a_self - m) : 0.f;
    for (int e = beg + lane; e < end; e += 64) ds += __expf(lrelu(as_v[col[e]] + adv) - m);
#pragma unroll
    for (int off = 32; off; off >>= 1) ds += __shfl_xor(ds, off);
    float inv = 1.f / ds;

    float cs = __expf(a_self - m) * inv;
    float acc = cs * Hf[(size_t)node * 64 + lane];

    for (int cb = beg; cb < end; cb += 64) {
        int idx = cb + lane;
        int sreg = 0; float creg = 0.f;
        if (idx < end) { sreg = col[idx]; creg = __expf(lrelu(as_v[sreg] + adv) - m) * inv; }
        int cnt = end - cb; if (cnt > 64) cnt = 64;
        int k = 0;
        for (; k + 4 <= cnt; k += 4) {
            int i0 = __shfl(sreg, k), i1 = __shfl(sreg, k + 1),
                i2 = __shfl(sreg, k + 2), i3 = __shfl(sreg, k + 3);
            float c0 = __shfl(creg, k), c1 = __shfl(creg, k + 1),
                  c2 = __shfl(creg, k + 2), c3 = __shfl(creg, k + 3);
            float p0 = Hf[(size_t)i0 * 64 + lane], p1 = Hf[(size_t)i1 * 64 + lane],
                  p2 = Hf[(size_t)i2 * 64 + lane], p3 = Hf[(size_t)i3 * 64 + lane];
            acc += c0 * p0; acc += c1 * p1; acc += c2 * p2; acc += c3 * p3;
        }
        for (; k < cnt; ++k) {
            int i0 = __shfl(sreg, k); float c0 = __shfl(creg, k);
            acc += c0 * Hf[(size_t)i0 * 64 + lane];
        }
    }

    float v = acc + bias[lane];
    float mx = v;
#pragma unroll
    for (int off = 32; off; off >>= 1) mx = fmaxf(mx, __shfl_xor(mx, off));
    float ex = __expf(v - mx);
    float sum = ex;
#pragma unroll
    for (int off = 32; off; off >>= 1) sum += __shfl_xor(sum, off);
    out[(size_t)node * 64 + lane] = v - mx - logf(sum);
}

extern "C" void kernel_launch(void* const* d_in, const int* in_sizes, int n_in,
                              void* d_out, int out_size, void* d_ws, size_t ws_size,
                              hipStream_t stream) {
    const float* x   = (const float*)d_in[0];
    const int*   ei  = (const int*)d_in[1];
    const float* W0  = (const float*)d_in[2];
    const float* as0 = (const float*)d_in[3];
    const float* ad0 = (const float*)d_in[4];
    const float* b0  = (const float*)d_in[5];
    const float* W1  = (const float*)d_in[6];
    const float* as1 = (const float*)d_in[7];
    const float* ad1 = (const float*)d_in[8];
    const float* b1  = (const float*)d_in[9];
    const float* W2  = (const float*)d_in[10];
    const float* as2 = (const float*)d_in[11];
    const float* ad2 = (const float*)d_in[12];
    const float* b2  = (const float*)d_in[13];

    int n = in_sizes[0] / 128;
    int E = in_sizes[1] / 2;
    const int* srcv = ei;
    const int* dstv = ei + E;

    char* wsp = (char*)d_ws;
    auto alloc = [&](size_t bytes) {
        char* p = wsp;
        wsp += (bytes + 255) & ~(size_t)255;
        return p;
    };
    int*   counts  = (int*)alloc((size_t)n * 4);
    int*   row_ptr = (int*)alloc((size_t)(n + 1) * 4);
    int*   cursor  = (int*)alloc((size_t)n * 4);
    int*   totals  = (int*)alloc(256 * 4);
    int*   col     = (int*)alloc((size_t)E * 4);
    unsigned short* wz0 = (unsigned short*)alloc(128 * 128 * 2);
    unsigned short* wz1 = (unsigned short*)alloc(128 * 128 * 2);
    unsigned short* wz2 = (unsigned short*)alloc(128 * 64 * 2);
    unsigned* hb   = (unsigned*)alloc((size_t)n * 64 * 4);       // bf16 h [n,128] packed
    float*    hf   = (float*)alloc((size_t)n * 64 * 4);          // fp32 h [n,64]
    unsigned* xb   = (unsigned*)alloc((size_t)n * 64 * 4);       // bf16 activations [n,128] packed
    float*    asb  = (float*)alloc((size_t)n * 4);
    float*    adb  = (float*)alloc((size_t)n * 4);

    // ---- CSR build ----
    (void)hipMemsetAsync(counts, 0, (size_t)n * 4, stream);
    int eb = (E + 255) / 256;
    count_kernel<<<eb, 256, 0, stream>>>(dstv, counts, E);
    int nb = (n + BS_SCAN - 1) / BS_SCAN;
    scan1_kernel<<<nb, BS_SCAN, 0, stream>>>(counts, row_ptr, totals, n);
    scan2_kernel<<<1, 256, 0, stream>>>(totals, nb);
    scan3_kernel<<<nb, BS_SCAN, 0, stream>>>(row_ptr, totals, cursor, n, E);
    scatter_kernel<<<eb, 256, 0, stream>>>(srcv, dstv, cursor, col, E);

    // ---- W swizzles ----
    wswz_kernel<<<(2048 + 255) / 256, 256, 0, stream>>>(W0, wz0, 128, 2048);
    wswz_kernel<<<(2048 + 255) / 256, 256, 0, stream>>>(W1, wz1, 128, 2048);
    wswz_kernel<<<(1024 + 255) / 256, 256, 0, stream>>>(W2, wz2, 64, 1024);

    int gemmb = (n + 63) / 64;
    int nodeb = (n + 3) / 4;

    // ---- layer 0 ----
    gemm_fused_kernel<128, false><<<gemmb, 256, 0, stream>>>(x, wz0, as0, ad0, hb, asb, adb, n);
    agg128_kernel<<<nodeb, 256, 0, stream>>>(hb, asb, adb, b0, row_ptr, col, xb, n);
    // ---- layer 1 ----
    gemm_fused_kernel<128, true><<<gemmb, 256, 0, stream>>>(xb, wz1, as1, ad1, hb, asb, adb, n);
    agg128_kernel<<<nodeb, 256, 0, stream>>>(hb, asb, adb, b1, row_ptr, col, xb, n);
    // ---- layer 2 ----
    gemm_fused_kernel<64, true><<<gemmb, 256, 0, stream>>>(xb, wz2, as2, ad2, hf, asb, adb, n);
    agg64_kernel<<<nodeb, 256, 0, stream>>>(hf, asb, adb, b2, row_ptr, col, (float*)d_out, n);
}

// Round 4
// 321.331 us; speedup vs baseline: 1.7952x; 1.0478x over previous
//
#include <hip/hip_runtime.h>
#include <math.h>

#define NEG_SLOPE 0.2f
constexpr int BS_SCAN = 1024;

typedef __attribute__((ext_vector_type(8))) short bfrag;   // 8 x bf16
typedef __attribute__((ext_vector_type(4))) float f32x4;

__device__ __forceinline__ float lrelu(float x) { return x > 0.f ? x : NEG_SLOPE * x; }

__device__ __forceinline__ unsigned short f2bf(float f) {
    union { float f; unsigned u; } v; v.f = f;
    unsigned r = v.u + 0x7fffu + ((v.u >> 16) & 1u);   // RNE
    return (unsigned short)(r >> 16);
}
__device__ __forceinline__ float bf2f_lo(unsigned p) { union { unsigned u; float f; } v; v.u = p << 16; return v.f; }
__device__ __forceinline__ float bf2f_hi(unsigned p) { union { unsigned u; float f; } v; v.u = p & 0xffff0000u; return v.f; }

// ---------------- CSR build (group edges by dst) ----------------
__global__ void count_kernel(const int* __restrict__ dst, int* __restrict__ counts, int E) {
    int e = blockIdx.x * blockDim.x + threadIdx.x;
    if (e < E) atomicAdd(&counts[dst[e]], 1);
}

__global__ void scan1_kernel(const int* __restrict__ counts, int* __restrict__ excl,
                             int* __restrict__ totals, int n) {
    __shared__ int sm[BS_SCAN];
    int tid = threadIdx.x;
    int i = blockIdx.x * BS_SCAN + tid;
    int v = (i < n) ? counts[i] : 0;
    int val = v;
    sm[tid] = val;
    for (int off = 1; off < BS_SCAN; off <<= 1) {
        __syncthreads();
        int t = (tid >= off) ? sm[tid - off] : 0;
        __syncthreads();
        val += t; sm[tid] = val;
    }
    if (i < n) excl[i] = val - v;
    if (tid == BS_SCAN - 1) totals[blockIdx.x] = val;
}

__global__ void scan2_kernel(int* totals, int nb) {
    __shared__ int sm[256];
    int tid = threadIdx.x;
    int v = (tid < nb) ? totals[tid] : 0;
    int val = v; sm[tid] = val;
    for (int off = 1; off < 256; off <<= 1) {
        __syncthreads();
        int t = (tid >= off) ? sm[tid - off] : 0;
        __syncthreads();
        val += t; sm[tid] = val;
    }
    if (tid < nb) totals[tid] = val - v;
}

__global__ void scan3_kernel(int* __restrict__ row_ptr, const int* __restrict__ totals,
                             int* __restrict__ cursor, int n, int E) {
    int i = blockIdx.x * BS_SCAN + threadIdx.x;
    if (i < n) {
        int rp = row_ptr[i] + totals[blockIdx.x];
        row_ptr[i] = rp;
        cursor[i] = rp;
    }
    if (i == 0) row_ptr[n] = E;
}

__global__ void scatter_kernel(const int* __restrict__ src, const int* __restrict__ dst,
                               int* __restrict__ cursor, int* __restrict__ col, int E) {
    int e = blockIdx.x * blockDim.x + threadIdx.x;
    if (e < E) {
        int d = dst[e];
        int pos = atomicAdd(&cursor[d], 1);
        col[pos] = src[e];
    }
}

// ---------------- W swizzle: fp32 [128,DOUT] -> bf16 B-fragment order ----------------
__global__ void wswz_kernel(const float* __restrict__ W, unsigned short* __restrict__ out,
                            int DOUT, int total) {
    int tid = blockIdx.x * blockDim.x + threadIdx.x;
    if (tid >= total) return;
    int lane = tid & 63;
    int g = tid >> 6;
    int NT = DOUT >> 4;
    int tile = g % NT, kstep = g / NT;
    int q = lane >> 4, c = lane & 15;
    int n_ = tile * 16 + c;
    unsigned short v[8];
#pragma unroll
    for (int j = 0; j < 8; ++j) {
        int k = kstep * 32 + q * 8 + j;
        v[j] = f2bf(W[k * DOUT + n_]);
    }
    uint4 o;
    o.x = (unsigned)v[0] | ((unsigned)v[1] << 16);
    o.y = (unsigned)v[2] | ((unsigned)v[3] << 16);
    o.z = (unsigned)v[4] | ((unsigned)v[5] << 16);
    o.w = (unsigned)v[6] | ((unsigned)v[7] << 16);
    *(uint4*)(out + (size_t)tid * 8) = o;
}

// ---------------- fused GEMM (bf16 MFMA) + attention dots ----------------
template<int DOUT, bool ABF>
__global__ __launch_bounds__(256) void gemm_fused_kernel(
    const void* __restrict__ Xv, const unsigned short* __restrict__ Wswz,
    const float* __restrict__ avs, const float* __restrict__ avd,
    void* __restrict__ Hout, float* __restrict__ as_out, float* __restrict__ ad_out, int n)
{
    constexpr int NT = DOUT / 16;
    __shared__ float smem[4][16 * 132];
    int w = threadIdx.x >> 6, lane = threadIdx.x & 63;
    int q = lane >> 4, c = lane & 15;
    int rowbase = blockIdx.x * 64 + w * 16;
    int arow = rowbase + c;

    f32x4 acc[NT];
#pragma unroll
    for (int t = 0; t < NT; ++t) acc[t] = (f32x4){0.f, 0.f, 0.f, 0.f};

#pragma unroll
    for (int ks = 0; ks < 4; ++ks) {
        bfrag a = (bfrag)0;
        int k0 = ks * 32 + q * 8;
        if (ABF) {
            if (arow < n) a = *(const bfrag*)((const unsigned short*)Xv + (size_t)arow * 128 + k0);
        } else {
            if (arow < n) {
                const float* xp = (const float*)Xv + (size_t)arow * 128 + k0;
                float4 x0 = *(const float4*)xp, x1 = *(const float4*)(xp + 4);
                a[0] = (short)f2bf(x0.x); a[1] = (short)f2bf(x0.y);
                a[2] = (short)f2bf(x0.z); a[3] = (short)f2bf(x0.w);
                a[4] = (short)f2bf(x1.x); a[5] = (short)f2bf(x1.y);
                a[6] = (short)f2bf(x1.z); a[7] = (short)f2bf(x1.w);
            }
        }
#pragma unroll
        for (int t = 0; t < NT; ++t) {
            bfrag b = *(const bfrag*)(Wswz + ((size_t)(ks * NT + t) * 64 + lane) * 8);
            acc[t] = __builtin_amdgcn_mfma_f32_16x16x32_bf16(a, b, acc[t], 0, 0, 0);
        }
    }

    float* sm = smem[w];
#pragma unroll
    for (int t = 0; t < NT; ++t)
#pragma unroll
        for (int r = 0; r < 4; ++r)
            sm[(q * 4 + r) * 132 + t * 16 + c] = acc[t][r];
    __builtin_amdgcn_wave_barrier();

    if (DOUT == 128) {
#pragma unroll
        for (int it = 0; it < 4; ++it) {
            int r = it * 4 + q;
            int grow = rowbase + r;
            const float* rp = sm + r * 132 + c * 8;
            float4 xa = *(const float4*)rp, xb4 = *(const float4*)(rp + 4);
            uint4 o;
            o.x = (unsigned)f2bf(xa.x) | ((unsigned)f2bf(xa.y) << 16);
            o.y = (unsigned)f2bf(xa.z) | ((unsigned)f2bf(xa.w) << 16);
            o.z = (unsigned)f2bf(xb4.x) | ((unsigned)f2bf(xb4.y) << 16);
            o.w = (unsigned)f2bf(xb4.z) | ((unsigned)f2bf(xb4.w) << 16);
            if (grow < n) *(uint4*)((unsigned*)Hout + (size_t)grow * 64 + c * 4) = o;
        }
    } else {
#pragma unroll
        for (int it = 0; it < 4; ++it) {
            int r = it * 4 + q;
            int grow = rowbase + r;
            float4 v = *(const float4*)(sm + r * 132 + c * 4);
            if (grow < n) *(float4*)((float*)Hout + (size_t)grow * 64 + c * 4) = v;
        }
    }

    int dr = lane >> 2;
    int c0 = (lane & 3) * (DOUT / 4);
    float s = 0.f, d = 0.f;
#pragma unroll
    for (int j = 0; j < DOUT / 4; j += 4) {
        float4 hv = *(const float4*)(sm + dr * 132 + c0 + j);
        float4 av = *(const float4*)(avs + c0 + j);
        float4 dv = *(const float4*)(avd + c0 + j);
        s += hv.x * av.x + hv.y * av.y + hv.z * av.z + hv.w * av.w;
        d += hv.x * dv.x + hv.y * dv.y + hv.z * dv.z + hv.w * dv.w;
    }
    s += __shfl_down(s, 2); s += __shfl_down(s, 1);
    d += __shfl_down(d, 2); d += __shfl_down(d, 1);
    int grow = rowbase + dr;
    if ((lane & 3) == 0 && grow < n) { as_out[grow] = s; ad_out[grow] = d; }
}

// ---------------- aggregation, DOUT=128, bf16 h, SiLU, bf16 out ----------------
// Wave per node; 4 edges in flight (16-lane groups), uint4 row slices.
// No segment-max (exp(a)/sum exp(a) directly, clamp 60); denom fused into single pass.
__global__ __launch_bounds__(256) void agg128_kernel(
    const unsigned* __restrict__ Hb, const float* __restrict__ as_v,
    const float* __restrict__ ad_v, const float* __restrict__ bias,
    const int* __restrict__ row_ptr, const int* __restrict__ col,
    unsigned* __restrict__ outb, int n)
{
    int lane = threadIdx.x & 63;
    int node = blockIdx.x * 4 + (threadIdx.x >> 6);
    if (node >= n) return;
    int g = lane >> 4, i = lane & 15;
    int beg = row_ptr[node], end = row_ptr[node + 1];
    float adv = ad_v[node];
    float c_self = __expf(fminf(lrelu(as_v[node] + adv), 60.f));

    // self-loop contribution (group 0 only; summed into all groups' slots later)
    uint4 hs = *(const uint4*)(Hb + (size_t)node * 64 + i * 4);
    float cs0 = (g == 0) ? c_self : 0.f;
    float acc[8];
    acc[0] = cs0 * bf2f_lo(hs.x); acc[1] = cs0 * bf2f_hi(hs.x);
    acc[2] = cs0 * bf2f_lo(hs.y); acc[3] = cs0 * bf2f_hi(hs.y);
    acc[4] = cs0 * bf2f_lo(hs.z); acc[5] = cs0 * bf2f_hi(hs.z);
    acc[6] = cs0 * bf2f_lo(hs.w); acc[7] = cs0 * bf2f_hi(hs.w);
    float dsum = (lane == 0) ? c_self : 0.f;

    for (int cb = beg; cb < end; cb += 64) {
        int idx = cb + lane;
        int sreg = 0; float creg = 0.f;
        if (idx < end) {
            sreg = col[idx];
            creg = __expf(fminf(lrelu(as_v[sreg] + adv), 60.f));
        }
        dsum += creg;
        int cnt = end - cb; if (cnt > 64) cnt = 64;
        for (int k = 0; k < cnt; k += 4) {
            int kk = k + g;
            int s = __shfl(sreg, kk);
            float c = (kk < cnt) ? __shfl(creg, kk) : 0.f;
            uint4 hp = *(const uint4*)(Hb + (size_t)s * 64 + i * 4);
            acc[0] += c * bf2f_lo(hp.x); acc[1] += c * bf2f_hi(hp.x);
            acc[2] += c * bf2f_lo(hp.y); acc[3] += c * bf2f_hi(hp.y);
            acc[4] += c * bf2f_lo(hp.z); acc[5] += c * bf2f_hi(hp.z);
            acc[6] += c * bf2f_lo(hp.w); acc[7] += c * bf2f_hi(hp.w);
        }
    }

#pragma unroll
    for (int off = 32; off; off >>= 1) dsum += __shfl_xor(dsum, off);
    float inv = 1.f / dsum;
#pragma unroll
    for (int j = 0; j < 8; ++j) { acc[j] += __shfl_xor(acc[j], 16); acc[j] += __shfl_xor(acc[j], 32); }

    if (g == 0) {
        float4 b0v = *(const float4*)(bias + i * 8);
        float4 b1v = *(const float4*)(bias + i * 8 + 4);
        float v0 = acc[0] * inv + b0v.x, v1 = acc[1] * inv + b0v.y;
        float v2 = acc[2] * inv + b0v.z, v3 = acc[3] * inv + b0v.w;
        float v4 = acc[4] * inv + b1v.x, v5 = acc[5] * inv + b1v.y;
        float v6 = acc[6] * inv + b1v.z, v7 = acc[7] * inv + b1v.w;
        v0 /= (1.f + __expf(-v0)); v1 /= (1.f + __expf(-v1));
        v2 /= (1.f + __expf(-v2)); v3 /= (1.f + __expf(-v3));
        v4 /= (1.f + __expf(-v4)); v5 /= (1.f + __expf(-v5));
        v6 /= (1.f + __expf(-v6)); v7 /= (1.f + __expf(-v7));
        uint4 o;
        o.x = (unsigned)f2bf(v0) | ((unsigned)f2bf(v1) << 16);
        o.y = (unsigned)f2bf(v2) | ((unsigned)f2bf(v3) << 16);
        o.z = (unsigned)f2bf(v4) | ((unsigned)f2bf(v5) << 16);
        o.w = (unsigned)f2bf(v6) | ((unsigned)f2bf(v7) << 16);
        *(uint4*)(outb + (size_t)node * 64 + i * 4) = o;
    }
}

// ---------------- aggregation, DOUT=64, fp32 h, log_softmax out ----------------
__global__ __launch_bounds__(256) void agg64_kernel(
    const float* __restrict__ Hf, const float* __restrict__ as_v,
    const float* __restrict__ ad_v, const float* __restrict__ bias,
    const int* __restrict__ row_ptr, const int* __restrict__ col,
    float* __restrict__ out, int n)
{
    int lane = threadIdx.x & 63;
    int node = blockIdx.x * 4 + (threadIdx.x >> 6);
    if (node >= n) return;
    int g = lane >> 4, i = lane & 15;
    int beg = row_ptr[node], end = row_ptr[node + 1];
    float adv = ad_v[node];
    float c_self = __expf(fminf(lrelu(as_v[node] + adv), 60.f));

    float4 hsv = *(const float4*)(Hf + (size_t)node * 64 + i * 4);
    float cs0 = (g == 0) ? c_self : 0.f;
    float acc[4] = {cs0 * hsv.x, cs0 * hsv.y, cs0 * hsv.z, cs0 * hsv.w};
    float dsum = (lane == 0) ? c_self : 0.f;

    for (int cb = beg; cb < end; cb += 64) {
        int idx = cb + lane;
        int sreg = 0; float creg = 0.f;
        if (idx < end) {
            sreg = col[idx];
            creg = __expf(fminf(lrelu(as_v[sreg] + adv), 60.f));
        }
        dsum += creg;
        int cnt = end - cb; if (cnt > 64) cnt = 64;
        for (int k = 0; k < cnt; k += 4) {
            int kk = k + g;
            int s = __shfl(sreg, kk);
            float c = (kk < cnt) ? __shfl(creg, kk) : 0.f;
            float4 hp = *(const float4*)(Hf + (size_t)s * 64 + i * 4);
            acc[0] += c * hp.x; acc[1] += c * hp.y;
            acc[2] += c * hp.z; acc[3] += c * hp.w;
        }
    }

#pragma unroll
    for (int off = 32; off; off >>= 1) dsum += __shfl_xor(dsum, off);
    float inv = 1.f / dsum;
#pragma unroll
    for (int j = 0; j < 4; ++j) { acc[j] += __shfl_xor(acc[j], 16); acc[j] += __shfl_xor(acc[j], 32); }

    float4 bv = *(const float4*)(bias + i * 4);
    float v0 = acc[0] * inv + bv.x, v1 = acc[1] * inv + bv.y;
    float v2 = acc[2] * inv + bv.z, v3 = acc[3] * inv + bv.w;
    // log_softmax over 64 classes: per-lane max/sum then cross-i (bits 0..3)
    float mx = fmaxf(fmaxf(v0, v1), fmaxf(v2, v3));
#pragma unroll
    for (int off = 8; off; off >>= 1) mx = fmaxf(mx, __shfl_xor(mx, off));
    float sum = __expf(v0 - mx) + __expf(v1 - mx) + __expf(v2 - mx) + __expf(v3 - mx);
#pragma unroll
    for (int off = 8; off; off >>= 1) sum += __shfl_xor(sum, off);
    float ls = mx + logf(sum);
    if (g == 0) {
        float4 o = make_float4(v0 - ls, v1 - ls, v2 - ls, v3 - ls);
        *(float4*)(out + (size_t)node * 64 + i * 4) = o;
    }
}

extern "C" void kernel_launch(void* const* d_in, const int* in_sizes, int n_in,
                              void* d_out, int out_size, void* d_ws, size_t ws_size,
                              hipStream_t stream) {
    const float* x   = (const float*)d_in[0];
    const int*   ei  = (const int*)d_in[1];
    const float* W0  = (const float*)d_in[2];
    const float* as0 = (const float*)d_in[3];
    const float* ad0 = (const float*)d_in[4];
    const float* b0  = (const float*)d_in[5];
    const float* W1  = (const float*)d_in[6];
    const float* as1 = (const float*)d_in[7];
    const float* ad1 = (const float*)d_in[8];
    const float* b1  = (const float*)d_in[9];
    const float* W2  = (const float*)d_in[10];
    const float* as2 = (const float*)d_in[11];
    const float* ad2 = (const float*)d_in[12];
    const float* b2  = (const float*)d_in[13];

    int n = in_sizes[0] / 128;
    int E = in_sizes[1] / 2;
    const int* srcv = ei;
    const int* dstv = ei + E;

    char* wsp = (char*)d_ws;
    auto alloc = [&](size_t bytes) {
        char* p = wsp;
        wsp += (bytes + 255) & ~(size_t)255;
        return p;
    };
    int*   counts  = (int*)alloc((size_t)n * 4);
    int*   row_ptr = (int*)alloc((size_t)(n + 1) * 4);
    int*   cursor  = (int*)alloc((size_t)n * 4);
    int*   totals  = (int*)alloc(256 * 4);
    int*   col     = (int*)alloc((size_t)E * 4);
    unsigned short* wz0 = (unsigned short*)alloc(128 * 128 * 2);
    unsigned short* wz1 = (unsigned short*)alloc(128 * 128 * 2);
    unsigned short* wz2 = (unsigned short*)alloc(128 * 64 * 2);
    unsigned* hb   = (unsigned*)alloc((size_t)n * 64 * 4);
    float*    hf   = (float*)alloc((size_t)n * 64 * 4);
    unsigned* xb   = (unsigned*)alloc((size_t)n * 64 * 4);
    float*    asb  = (float*)alloc((size_t)n * 4);
    float*    adb  = (float*)alloc((size_t)n * 4);

    // ---- CSR build ----
    (void)hipMemsetAsync(counts, 0, (size_t)n * 4, stream);
    int eb = (E + 255) / 256;
    count_kernel<<<eb, 256, 0, stream>>>(dstv, counts, E);
    int nb = (n + BS_SCAN - 1) / BS_SCAN;
    scan1_kernel<<<nb, BS_SCAN, 0, stream>>>(counts, row_ptr, totals, n);
    scan2_kernel<<<1, 256, 0, stream>>>(totals, nb);
    scan3_kernel<<<nb, BS_SCAN, 0, stream>>>(row_ptr, totals, cursor, n, E);
    scatter_kernel<<<eb, 256, 0, stream>>>(srcv, dstv, cursor, col, E);

    // ---- W swizzles ----
    wswz_kernel<<<(2048 + 255) / 256, 256, 0, stream>>>(W0, wz0, 128, 2048);
    wswz_kernel<<<(2048 + 255) / 256, 256, 0, stream>>>(W1, wz1, 128, 2048);
    wswz_kernel<<<(1024 + 255) / 256, 256, 0, stream>>>(W2, wz2, 64, 1024);

    int gemmb = (n + 63) / 64;
    int nodeb = (n + 3) / 4;

    // ---- layer 0 ----
    gemm_fused_kernel<128, false><<<gemmb, 256, 0, stream>>>(x, wz0, as0, ad0, hb, asb, adb, n);
    agg128_kernel<<<nodeb, 256, 0, stream>>>(hb, asb, adb, b0, row_ptr, col, xb, n);
    // ---- layer 1 ----
    gemm_fused_kernel<128, true><<<gemmb, 256, 0, stream>>>(xb, wz1, as1, ad1, hb, asb, adb, n);
    agg128_kernel<<<nodeb, 256, 0, stream>>>(hb, asb, adb, b1, row_ptr, col, xb, n);
    // ---- layer 2 ----
    gemm_fused_kernel<64, true><<<gemmb, 256, 0, stream>>>(xb, wz2, as2, ad2, hf, asb, adb, n);
    agg64_kernel<<<nodeb, 256, 0, stream>>>(hf, asb, adb, b2, row_ptr, col, (float*)d_out, n);
}

// Round 5
// 304.874 us; speedup vs baseline: 1.8921x; 1.0540x over previous
//
#include <hip/hip_runtime.h>
#include <math.h>

#define NEG_SLOPE 0.2f
constexpr int BS_SCAN = 1024;

typedef __attribute__((ext_vector_type(8))) short bfrag;   // 8 x bf16
typedef __attribute__((ext_vector_type(4))) float f32x4;

__device__ __forceinline__ float lrelu(float x) { return x > 0.f ? x : NEG_SLOPE * x; }

__device__ __forceinline__ unsigned short f2bf(float f) {
    union { float f; unsigned u; } v; v.f = f;
    unsigned r = v.u + 0x7fffu + ((v.u >> 16) & 1u);   // RNE
    return (unsigned short)(r >> 16);
}
__device__ __forceinline__ float bf2f_lo(unsigned p) { union { unsigned u; float f; } v; v.u = p << 16; return v.f; }
__device__ __forceinline__ float bf2f_hi(unsigned p) { union { unsigned u; float f; } v; v.u = p & 0xffff0000u; return v.f; }

// ---------------- prep: edge count (CSR) + all 3 W swizzles in one launch ----------------
__device__ __forceinline__ void wswz_body(const float* __restrict__ W, unsigned short* __restrict__ out,
                                          int DOUT, int tid) {
    int lane = tid & 63;
    int g = tid >> 6;
    int NT = DOUT >> 4;
    int tile = g % NT, kstep = g / NT;
    int q = lane >> 4, c = lane & 15;
    int n_ = tile * 16 + c;
    unsigned short v[8];
#pragma unroll
    for (int j = 0; j < 8; ++j) {
        int k = kstep * 32 + q * 8 + j;
        v[j] = f2bf(W[k * DOUT + n_]);
    }
    uint4 o;
    o.x = (unsigned)v[0] | ((unsigned)v[1] << 16);
    o.y = (unsigned)v[2] | ((unsigned)v[3] << 16);
    o.z = (unsigned)v[4] | ((unsigned)v[5] << 16);
    o.w = (unsigned)v[6] | ((unsigned)v[7] << 16);
    *(uint4*)(out + (size_t)tid * 8) = o;
}

__global__ void prep_kernel(const int* __restrict__ dst, int* __restrict__ counts, int E, int eb,
                            const float* __restrict__ W0, const float* __restrict__ W1,
                            const float* __restrict__ W2,
                            unsigned short* __restrict__ wz0, unsigned short* __restrict__ wz1,
                            unsigned short* __restrict__ wz2) {
    int b = blockIdx.x;
    if (b < eb) {
        int e = b * blockDim.x + threadIdx.x;
        if (e < E) atomicAdd(&counts[dst[e]], 1);
    } else {
        int wb = b - eb;                   // 0..19
        if (wb < 8)       wswz_body(W0, wz0, 128, wb * 256 + threadIdx.x);
        else if (wb < 16) wswz_body(W1, wz1, 128, (wb - 8) * 256 + threadIdx.x);
        else {
            int tid = (wb - 16) * 256 + threadIdx.x;
            if (tid < 1024) wswz_body(W2, wz2, 64, tid);
        }
    }
}

// ---------------- scan phase 1: per-block exclusive scan of counts ----------------
__global__ void scan1_kernel(const int* __restrict__ counts, int* __restrict__ excl,
                             int* __restrict__ totals, int n) {
    __shared__ int sm[BS_SCAN];
    int tid = threadIdx.x;
    int i = blockIdx.x * BS_SCAN + tid;
    int v = (i < n) ? counts[i] : 0;
    int val = v;
    sm[tid] = val;
    for (int off = 1; off < BS_SCAN; off <<= 1) {
        __syncthreads();
        int t = (tid >= off) ? sm[tid - off] : 0;
        __syncthreads();
        val += t; sm[tid] = val;
    }
    if (i < n) excl[i] = val - v;
    if (tid == BS_SCAN - 1) totals[blockIdx.x] = val;
}

// ---------------- scan phase 2+3 fused: add block offset (redundant mini-reduce) ----------------
__global__ void scan23_kernel(int* __restrict__ row_ptr, const int* __restrict__ totals,
                              int* __restrict__ cursor, int n, int E, int nb) {
    __shared__ int s_off;
    int tid = threadIdx.x;
    if (tid < 64) {
        int v = (tid < blockIdx.x && tid < nb) ? totals[tid] : 0;
#pragma unroll
        for (int off = 32; off; off >>= 1) v += __shfl_xor(v, off);
        if (tid == 0) s_off = v;
    }
    __syncthreads();
    int off = s_off;
    int i = blockIdx.x * BS_SCAN + tid;
    if (i < n) {
        int rp = row_ptr[i] + off;
        row_ptr[i] = rp;
        cursor[i] = rp;
    }
    if (i == 0) row_ptr[n] = E;
}

__global__ void scatter_kernel(const int* __restrict__ src, const int* __restrict__ dst,
                               int* __restrict__ cursor, unsigned short* __restrict__ col, int E) {
    int e = blockIdx.x * blockDim.x + threadIdx.x;
    if (e < E) {
        int d = dst[e];
        int pos = atomicAdd(&cursor[d], 1);
        col[pos] = (unsigned short)src[e];
    }
}

// ---------------- fused GEMM (bf16 MFMA) + attention dots ----------------
template<int DOUT, bool ABF>
__global__ __launch_bounds__(256) void gemm_fused_kernel(
    const void* __restrict__ Xv, const unsigned short* __restrict__ Wswz,
    const float* __restrict__ avs, const float* __restrict__ avd,
    void* __restrict__ Hout, float* __restrict__ as_out, float* __restrict__ ad_out, int n)
{
    constexpr int NT = DOUT / 16;
    __shared__ float smem[4][16 * 132];
    int w = threadIdx.x >> 6, lane = threadIdx.x & 63;
    int q = lane >> 4, c = lane & 15;
    int rowbase = blockIdx.x * 64 + w * 16;
    int arow = rowbase + c;

    f32x4 acc[NT];
#pragma unroll
    for (int t = 0; t < NT; ++t) acc[t] = (f32x4){0.f, 0.f, 0.f, 0.f};

#pragma unroll
    for (int ks = 0; ks < 4; ++ks) {
        bfrag a = (bfrag)0;
        int k0 = ks * 32 + q * 8;
        if (ABF) {
            if (arow < n) a = *(const bfrag*)((const unsigned short*)Xv + (size_t)arow * 128 + k0);
        } else {
            if (arow < n) {
                const float* xp = (const float*)Xv + (size_t)arow * 128 + k0;
                float4 x0 = *(const float4*)xp, x1 = *(const float4*)(xp + 4);
                a[0] = (short)f2bf(x0.x); a[1] = (short)f2bf(x0.y);
                a[2] = (short)f2bf(x0.z); a[3] = (short)f2bf(x0.w);
                a[4] = (short)f2bf(x1.x); a[5] = (short)f2bf(x1.y);
                a[6] = (short)f2bf(x1.z); a[7] = (short)f2bf(x1.w);
            }
        }
#pragma unroll
        for (int t = 0; t < NT; ++t) {
            bfrag b = *(const bfrag*)(Wswz + ((size_t)(ks * NT + t) * 64 + lane) * 8);
            acc[t] = __builtin_amdgcn_mfma_f32_16x16x32_bf16(a, b, acc[t], 0, 0, 0);
        }
    }

    float* sm = smem[w];
#pragma unroll
    for (int t = 0; t < NT; ++t)
#pragma unroll
        for (int r = 0; r < 4; ++r)
            sm[(q * 4 + r) * 132 + t * 16 + c] = acc[t][r];
    __builtin_amdgcn_wave_barrier();

    if (DOUT == 128) {
#pragma unroll
        for (int it = 0; it < 4; ++it) {
            int r = it * 4 + q;
            int grow = rowbase + r;
            const float* rp = sm + r * 132 + c * 8;
            float4 xa = *(const float4*)rp, xb4 = *(const float4*)(rp + 4);
            uint4 o;
            o.x = (unsigned)f2bf(xa.x) | ((unsigned)f2bf(xa.y) << 16);
            o.y = (unsigned)f2bf(xa.z) | ((unsigned)f2bf(xa.w) << 16);
            o.z = (unsigned)f2bf(xb4.x) | ((unsigned)f2bf(xb4.y) << 16);
            o.w = (unsigned)f2bf(xb4.z) | ((unsigned)f2bf(xb4.w) << 16);
            if (grow < n) *(uint4*)((unsigned*)Hout + (size_t)grow * 64 + c * 4) = o;
        }
    } else {
#pragma unroll
        for (int it = 0; it < 4; ++it) {
            int r = it * 4 + q;
            int grow = rowbase + r;
            float4 v = *(const float4*)(sm + r * 132 + c * 4);
            if (grow < n) *(float4*)((float*)Hout + (size_t)grow * 64 + c * 4) = v;
        }
    }

    int dr = lane >> 2;
    int c0 = (lane & 3) * (DOUT / 4);
    float s = 0.f, d = 0.f;
#pragma unroll
    for (int j = 0; j < DOUT / 4; j += 4) {
        float4 hv = *(const float4*)(sm + dr * 132 + c0 + j);
        float4 av = *(const float4*)(avs + c0 + j);
        float4 dv = *(const float4*)(avd + c0 + j);
        s += hv.x * av.x + hv.y * av.y + hv.z * av.z + hv.w * av.w;
        d += hv.x * dv.x + hv.y * dv.y + hv.z * dv.z + hv.w * dv.w;
    }
    s += __shfl_down(s, 2); s += __shfl_down(s, 1);
    d += __shfl_down(d, 2); d += __shfl_down(d, 1);
    int grow = rowbase + dr;
    if ((lane & 3) == 0 && grow < n) { as_out[grow] = s; ad_out[grow] = d; }
}

// ---------------- aggregation, DOUT=128, bf16 h, SiLU, bf16 out ----------------
// Wave per node; 8 edges in flight (4x16-lane groups, 2x unroll), uint4 row slices.
__global__ __launch_bounds__(256) void agg128_kernel(
    const unsigned* __restrict__ Hb, const float* __restrict__ as_v,
    const float* __restrict__ ad_v, const float* __restrict__ bias,
    const int* __restrict__ row_ptr, const unsigned short* __restrict__ col,
    unsigned* __restrict__ outb, int n)
{
    int lane = threadIdx.x & 63;
    int node = blockIdx.x * 4 + (threadIdx.x >> 6);
    if (node >= n) return;
    int g = lane >> 4, i = lane & 15;
    int beg = row_ptr[node], end = row_ptr[node + 1];
    float adv = ad_v[node];
    float c_self = __expf(fminf(lrelu(as_v[node] + adv), 60.f));

    uint4 hs = *(const uint4*)(Hb + (size_t)node * 64 + i * 4);
    float cs0 = (g == 0) ? c_self : 0.f;
    float acc[8];
    acc[0] = cs0 * bf2f_lo(hs.x); acc[1] = cs0 * bf2f_hi(hs.x);
    acc[2] = cs0 * bf2f_lo(hs.y); acc[3] = cs0 * bf2f_hi(hs.y);
    acc[4] = cs0 * bf2f_lo(hs.z); acc[5] = cs0 * bf2f_hi(hs.z);
    acc[6] = cs0 * bf2f_lo(hs.w); acc[7] = cs0 * bf2f_hi(hs.w);
    float dsum = (lane == 0) ? c_self : 0.f;

    for (int cb = beg; cb < end; cb += 64) {
        int idx = cb + lane;
        int sreg = 0; float creg = 0.f;
        if (idx < end) {
            sreg = col[idx];
            creg = __expf(fminf(lrelu(as_v[sreg] + adv), 60.f));
        }
        dsum += creg;
        int cnt = end - cb; if (cnt > 64) cnt = 64;
        for (int k = 0; k < cnt; k += 8) {
            int kk0 = k + g, kk1 = k + g + 4;
            int s0 = __shfl(sreg, kk0);
            int s1 = __shfl(sreg, kk1);
            float c0 = __shfl(creg, kk0);        // lanes >= cnt carry creg=0
            float c1 = __shfl(creg, kk1);
            uint4 h0 = *(const uint4*)(Hb + (size_t)s0 * 64 + i * 4);
            uint4 h1 = *(const uint4*)(Hb + (size_t)s1 * 64 + i * 4);
            acc[0] += c0 * bf2f_lo(h0.x); acc[1] += c0 * bf2f_hi(h0.x);
            acc[2] += c0 * bf2f_lo(h0.y); acc[3] += c0 * bf2f_hi(h0.y);
            acc[4] += c0 * bf2f_lo(h0.z); acc[5] += c0 * bf2f_hi(h0.z);
            acc[6] += c0 * bf2f_lo(h0.w); acc[7] += c0 * bf2f_hi(h0.w);
            acc[0] += c1 * bf2f_lo(h1.x); acc[1] += c1 * bf2f_hi(h1.x);
            acc[2] += c1 * bf2f_lo(h1.y); acc[3] += c1 * bf2f_hi(h1.y);
            acc[4] += c1 * bf2f_lo(h1.z); acc[5] += c1 * bf2f_hi(h1.z);
            acc[6] += c1 * bf2f_lo(h1.w); acc[7] += c1 * bf2f_hi(h1.w);
        }
    }

#pragma unroll
    for (int off = 32; off; off >>= 1) dsum += __shfl_xor(dsum, off);
    float inv = 1.f / dsum;
#pragma unroll
    for (int j = 0; j < 8; ++j) { acc[j] += __shfl_xor(acc[j], 16); acc[j] += __shfl_xor(acc[j], 32); }

    if (g == 0) {
        float4 b0v = *(const float4*)(bias + i * 8);
        float4 b1v = *(const float4*)(bias + i * 8 + 4);
        float v0 = acc[0] * inv + b0v.x, v1 = acc[1] * inv + b0v.y;
        float v2 = acc[2] * inv + b0v.z, v3 = acc[3] * inv + b0v.w;
        float v4 = acc[4] * inv + b1v.x, v5 = acc[5] * inv + b1v.y;
        float v6 = acc[6] * inv + b1v.z, v7 = acc[7] * inv + b1v.w;
        v0 /= (1.f + __expf(-v0)); v1 /= (1.f + __expf(-v1));
        v2 /= (1.f + __expf(-v2)); v3 /= (1.f + __expf(-v3));
        v4 /= (1.f + __expf(-v4)); v5 /= (1.f + __expf(-v5));
        v6 /= (1.f + __expf(-v6)); v7 /= (1.f + __expf(-v7));
        uint4 o;
        o.x = (unsigned)f2bf(v0) | ((unsigned)f2bf(v1) << 16);
        o.y = (unsigned)f2bf(v2) | ((unsigned)f2bf(v3) << 16);
        o.z = (unsigned)f2bf(v4) | ((unsigned)f2bf(v5) << 16);
        o.w = (unsigned)f2bf(v6) | ((unsigned)f2bf(v7) << 16);
        *(uint4*)(outb + (size_t)node * 64 + i * 4) = o;
    }
}

// ---------------- aggregation, DOUT=64, fp32 h, log_softmax out ----------------
__global__ __launch_bounds__(256) void agg64_kernel(
    const float* __restrict__ Hf, const float* __restrict__ as_v,
    const float* __restrict__ ad_v, const float* __restrict__ bias,
    const int* __restrict__ row_ptr, const unsigned short* __restrict__ col,
    float* __restrict__ out, int n)
{
    int lane = threadIdx.x & 63;
    int node = blockIdx.x * 4 + (threadIdx.x >> 6);
    if (node >= n) return;
    int g = lane >> 4, i = lane & 15;
    int beg = row_ptr[node], end = row_ptr[node + 1];
    float adv = ad_v[node];
    float c_self = __expf(fminf(lrelu(as_v[node] + adv), 60.f));

    float4 hsv = *(const float4*)(Hf + (size_t)node * 64 + i * 4);
    float cs0 = (g == 0) ? c_self : 0.f;
    float acc[4] = {cs0 * hsv.x, cs0 * hsv.y, cs0 * hsv.z, cs0 * hsv.w};
    float dsum = (lane == 0) ? c_self : 0.f;

    for (int cb = beg; cb < end; cb += 64) {
        int idx = cb + lane;
        int sreg = 0; float creg = 0.f;
        if (idx < end) {
            sreg = col[idx];
            creg = __expf(fminf(lrelu(as_v[sreg] + adv), 60.f));
        }
        dsum += creg;
        int cnt = end - cb; if (cnt > 64) cnt = 64;
        for (int k = 0; k < cnt; k += 8) {
            int kk0 = k + g, kk1 = k + g + 4;
            int s0 = __shfl(sreg, kk0);
            int s1 = __shfl(sreg, kk1);
            float c0 = __shfl(creg, kk0);
            float c1 = __shfl(creg, kk1);
            float4 h0 = *(const float4*)(Hf + (size_t)s0 * 64 + i * 4);
            float4 h1 = *(const float4*)(Hf + (size_t)s1 * 64 + i * 4);
            acc[0] += c0 * h0.x; acc[1] += c0 * h0.y;
            acc[2] += c0 * h0.z; acc[3] += c0 * h0.w;
            acc[0] += c1 * h1.x; acc[1] += c1 * h1.y;
            acc[2] += c1 * h1.z; acc[3] += c1 * h1.w;
        }
    }

#pragma unroll
    for (int off = 32; off; off >>= 1) dsum += __shfl_xor(dsum, off);
    float inv = 1.f / dsum;
#pragma unroll
    for (int j = 0; j < 4; ++j) { acc[j] += __shfl_xor(acc[j], 16); acc[j] += __shfl_xor(acc[j], 32); }

    float4 bv = *(const float4*)(bias + i * 4);
    float v0 = acc[0] * inv + bv.x, v1 = acc[1] * inv + bv.y;
    float v2 = acc[2] * inv + bv.z, v3 = acc[3] * inv + bv.w;
    float mx = fmaxf(fmaxf(v0, v1), fmaxf(v2, v3));
#pragma unroll
    for (int off = 8; off; off >>= 1) mx = fmaxf(mx, __shfl_xor(mx, off));
    float sum = __expf(v0 - mx) + __expf(v1 - mx) + __expf(v2 - mx) + __expf(v3 - mx);
#pragma unroll
    for (int off = 8; off; off >>= 1) sum += __shfl_xor(sum, off);
    float ls = mx + logf(sum);
    if (g == 0) {
        float4 o = make_float4(v0 - ls, v1 - ls, v2 - ls, v3 - ls);
        *(float4*)(out + (size_t)node * 64 + i * 4) = o;
    }
}

extern "C" void kernel_launch(void* const* d_in, const int* in_sizes, int n_in,
                              void* d_out, int out_size, void* d_ws, size_t ws_size,
                              hipStream_t stream) {
    const float* x   = (const float*)d_in[0];
    const int*   ei  = (const int*)d_in[1];
    const float* W0  = (const float*)d_in[2];
    const float* as0 = (const float*)d_in[3];
    const float* ad0 = (const float*)d_in[4];
    const float* b0  = (const float*)d_in[5];
    const float* W1  = (const float*)d_in[6];
    const float* as1 = (const float*)d_in[7];
    const float* ad1 = (const float*)d_in[8];
    const float* b1  = (const float*)d_in[9];
    const float* W2  = (const float*)d_in[10];
    const float* as2 = (const float*)d_in[11];
    const float* ad2 = (const float*)d_in[12];
    const float* b2  = (const float*)d_in[13];

    int n = in_sizes[0] / 128;
    int E = in_sizes[1] / 2;
    const int* srcv = ei;
    const int* dstv = ei + E;

    char* wsp = (char*)d_ws;
    auto alloc = [&](size_t bytes) {
        char* p = wsp;
        wsp += (bytes + 255) & ~(size_t)255;
        return p;
    };
    int*   counts  = (int*)alloc((size_t)n * 4);
    int*   row_ptr = (int*)alloc((size_t)(n + 1) * 4);
    int*   cursor  = (int*)alloc((size_t)n * 4);
    int*   totals  = (int*)alloc(256 * 4);
    unsigned short* col = (unsigned short*)alloc((size_t)E * 2);
    unsigned short* wz0 = (unsigned short*)alloc(128 * 128 * 2);
    unsigned short* wz1 = (unsigned short*)alloc(128 * 128 * 2);
    unsigned short* wz2 = (unsigned short*)alloc(128 * 64 * 2);
    unsigned* hb   = (unsigned*)alloc((size_t)n * 64 * 4);
    float*    hf   = (float*)alloc((size_t)n * 64 * 4);
    unsigned* xb   = (unsigned*)alloc((size_t)n * 64 * 4);
    float*    asb  = (float*)alloc((size_t)n * 4);
    float*    adb  = (float*)alloc((size_t)n * 4);

    // ---- CSR build + W swizzle prep ----
    (void)hipMemsetAsync(counts, 0, (size_t)n * 4, stream);
    int eb = (E + 255) / 256;
    prep_kernel<<<eb + 20, 256, 0, stream>>>(dstv, counts, E, eb, W0, W1, W2, wz0, wz1, wz2);
    int nb = (n + BS_SCAN - 1) / BS_SCAN;   // 49 <= 64 (scan23 wave-reduce bound)
    scan1_kernel<<<nb, BS_SCAN, 0, stream>>>(counts, row_ptr, totals, n);
    scan23_kernel<<<nb, BS_SCAN, 0, stream>>>(row_ptr, totals, cursor, n, E, nb);
    scatter_kernel<<<eb, 256, 0, stream>>>(srcv, dstv, cursor, col, E);

    int gemmb = (n + 63) / 64;
    int nodeb = (n + 3) / 4;

    // ---- layer 0 ----
    gemm_fused_kernel<128, false><<<gemmb, 256, 0, stream>>>(x, wz0, as0, ad0, hb, asb, adb, n);
    agg128_kernel<<<nodeb, 256, 0, stream>>>(hb, asb, adb, b0, row_ptr, col, xb, n);
    // ---- layer 1 ----
    gemm_fused_kernel<128, true><<<gemmb, 256, 0, stream>>>(xb, wz1, as1, ad1, hb, asb, adb, n);
    agg128_kernel<<<nodeb, 256, 0, stream>>>(hb, asb, adb, b1, row_ptr, col, xb, n);
    // ---- layer 2 ----
    gemm_fused_kernel<64, true><<<gemmb, 256, 0, stream>>>(xb, wz2, as2, ad2, hf, asb, adb, n);
    agg64_kernel<<<nodeb, 256, 0, stream>>>(hf, asb, adb, b2, row_ptr, col, (float*)d_out, n);
}